// Round 13
// baseline (412.422 us; speedup 1.0000x reference)
//
#include <hip/hip_runtime.h>
#include <math.h>

#define TINYF 1.17549435e-38f
#define GMAX 16.0f   // hard upper bound on gumbel (15.9424) + slack
#define NTILES 1563  // ceil(50000/32)
#define TPB 25       // tiles per span (64 spans x 25 >= 1563)

typedef __attribute__((ext_vector_type(8))) short bf16x8;
typedef __attribute__((ext_vector_type(4))) float f32x4;

// ---------------- threefry2x32, key = (0, 42) ----------------
__device__ __forceinline__ unsigned rotl32(unsigned x, int r) {
  return (x << r) | (x >> (32 - r));
}

__device__ __forceinline__ unsigned tf2x32_xor(unsigned x0, unsigned x1) {
  const unsigned k0 = 0u, k1 = 42u, k2 = 0x1BD11BF0u;  // 0x1BD11BDA ^ 0 ^ 42
  x0 += k0; x1 += k1;
#define TFR(r) { x0 += x1; x1 = rotl32(x1, r); x1 ^= x0; }
  TFR(13) TFR(15) TFR(26) TFR(6)
  x0 += k1; x1 += k2 + 1u;
  TFR(17) TFR(29) TFR(16) TFR(24)
  x0 += k2; x1 += k0 + 2u;
  TFR(13) TFR(15) TFR(26) TFR(6)
  x0 += k0; x1 += k1 + 3u;
  TFR(17) TFR(29) TFR(16) TFR(24)
  x0 += k1; x1 += k2 + 4u;
  TFR(13) TFR(15) TFR(26) TFR(6)
  x0 += k2; x1 += k0 + 5u;
#undef TFR
  return x0 ^ x1;
}

__device__ __forceinline__ float gumbel_from_bits(unsigned bits) {
  float f = __uint_as_float((bits >> 9) | 0x3f800000u) - 1.0f;
  float u = fmaxf(f, TINYF);
  return -logf(-logf(u));
}

// order-preserving float->uint (monotone)
__device__ __forceinline__ unsigned ordf(float v) {
  unsigned b = __float_as_uint(v);
  return (b & 0x80000000u) ? ~b : (b | 0x80000000u);
}
__device__ __forceinline__ float unordf(unsigned u) {
  unsigned b = (u & 0x80000000u) ? (u & 0x7FFFFFFFu) : ~u;
  return __uint_as_float(b);
}

// fp32 -> bf16 RNE (bit trick)
__device__ __forceinline__ unsigned short f2bf(float f) {
  unsigned u = __float_as_uint(f);
  unsigned r = u + 0x7FFFu + ((u >> 16) & 1u);
  return (unsigned short)(r >> 16);
}
__device__ __forceinline__ unsigned pk2(float a, float b) {
  return (unsigned)f2bf(a) | ((unsigned)f2bf(b) << 16);
}
// LDS XOR swizzle for 256B-row tile (breaks 32-way ds_read_b128 conflict)
__device__ __forceinline__ int bswz(int b) { return b ^ (((b >> 8) & 7) << 4); }

// ---- candidate resolution. Fresh tier-2 threshold from rowslot (tighter,
// still sound). Fast u-space pre-test with HW exp (no false reject, ~2e-5
// over-accept filtered by the exact path). ONE noinline copy, dense drains.
__device__ __attribute__((noinline)) void resolve_cand(
    int R, int J, float s, float ERRC,
    const float* __restrict__ hfin, const float* __restrict__ items,
    const float* __restrict__ V0,
    unsigned long long* __restrict__ rowslot, const volatile unsigned* hiw) {
  const unsigned hi0 = hiw[2 * R + 1];
  float tv = V0[R];
  if (hi0) tv = fmaxf(tv, unordf(hi0));
  const float thr2 = tv - ERRC;  // sound: s_fp32 + g <= s_bf16 + ERRC + g
  const float d = thr2 - s;
  const unsigned bits = tf2x32_xor(0u, (unsigned)R * 50000u + (unsigned)J);
  const float f = __uint_as_float((bits >> 9) | 0x3f800000u) - 1.0f;
  const float u = fmaxf(f, TINYF);
  const float thr_u = __expf(-__expf(-d)) * (1.0f - 2e-5f);
  if (u < thr_u) return;             // sound fast reject
  const float g = -logf(-logf(u));   // exact gumbel (rare path)
  if (s + g < thr2) return;          // exact tier-2
  const float4* hp = (const float4*)(hfin + (size_t)R * 128);
  const float4* ap = (const float4*)(items + (size_t)J * 128);
  float4 a4 = {0.f, 0.f, 0.f, 0.f};
#pragma unroll
  for (int k = 0; k < 32; ++k) {
    float4 h = hp[k];
    float4 b = ap[k];
    a4.x = fmaf(h.x, b.x, a4.x);
    a4.y = fmaf(h.y, b.y, a4.y);
    a4.z = fmaf(h.z, b.z, a4.z);
    a4.w = fmaf(h.w, b.w, a4.w);
  }
  const float v = ((a4.x + a4.y) + (a4.z + a4.w)) + g;
  const unsigned ov = ordf(v);
  if (ov >= hiw[2 * R + 1]) {  // '>=': let atomicMax resolve smaller-J ties
    const unsigned long long pk =
        ((unsigned long long)ov << 32) | (0xFFFFFFFFu - (unsigned)J);
    atomicMax(&rowslot[R], pk);
  }
}

// ---------------- items fp32 -> bf16 (once; same RNE bits as staging) ------
__global__ void k_bconv(const float* __restrict__ items,
                        unsigned short* __restrict__ ib) {
  const int e = (blockIdx.x * 256 + threadIdx.x) * 8;  // grid 3125 exact
  const float4 a = *(const float4*)(items + e);
  const float4 b = *(const float4*)(items + e + 4);
  uint4 o;
  o.x = pk2(a.x, a.y); o.y = pk2(a.z, a.w);
  o.z = pk2(b.x, b.y); o.w = pk2(b.z, b.w);
  *(uint4*)(ib + e) = o;
}

// ---------------- h = x @ W + b (f64 accumulate) + workspace init ----------
__global__ void k_hraw(const float* __restrict__ x, const float* __restrict__ W,
                       const float* __restrict__ b, float* __restrict__ hraw,
                       unsigned long long* __restrict__ rowslot,
                       float* __restrict__ norms) {
  __shared__ float sx[256];
  const int i = blockIdx.x;
  const int d = threadIdx.x;  // 128 threads
  if (d == 0) {
    rowslot[i] = 0ull;
    if (i == 0) { norms[0] = 0.0f; norms[1] = 0.0f; }
  }
  sx[d] = x[i * 256 + d];
  sx[d + 128] = x[i * 256 + 128 + d];
  __syncthreads();
  double acc = 0.0;
  for (int k = 0; k < 256; ++k)
    acc = fma((double)sx[k], (double)W[k * 128 + d], acc);
  hraw[i * 128 + d] = (float)acc + b[d];
}

// ---------------- BN stats per column (f64) ----------------
__global__ void k_bnstats(const float* __restrict__ hraw,
                          float* __restrict__ meanv, float* __restrict__ rsv) {
  __shared__ double red[256];
  const int d = blockIdx.x;   // 128 blocks
  const int t = threadIdx.x;  // 256 threads
  double s = 0.0;
  for (int i = t; i < 2048; i += 256) s += (double)hraw[i * 128 + d];
  red[t] = s;
  __syncthreads();
  for (int off = 128; off > 0; off >>= 1) {
    if (t < off) red[t] += red[t + off];
    __syncthreads();
  }
  const float m = (float)(red[0] * (1.0 / 2048.0));
  __syncthreads();
  double v = 0.0;
  for (int i = t; i < 2048; i += 256) {
    float dd = __fsub_rn(hraw[i * 128 + d], m);
    v += (double)dd * (double)dd;
  }
  red[t] = v;
  __syncthreads();
  for (int off = 128; off > 0; off >>= 1) {
    if (t < off) red[t] += red[t + off];
    __syncthreads();
  }
  if (t == 0) {
    float var = (float)(red[0] * (1.0 / 2048.0));
    float vpe = __fadd_rn(var, 1e-5f);
    meanv[d] = m;
    rsv[d] = (float)(1.0 / sqrt((double)vpe));
  }
}

// ---------------- apply BN + leaky relu, emit bf16 copy + max row-norm ------
__global__ void k_apply(const float* __restrict__ hraw,
                        const float* __restrict__ meanv, const float* __restrict__ rsv,
                        const float* __restrict__ gamma, const float* __restrict__ beta,
                        float* __restrict__ hfin, unsigned short* __restrict__ hb,
                        float* __restrict__ norms) {
  __shared__ float red[256];
  const int t = threadIdx.x;
  const int idx = blockIdx.x * 256 + t;  // 2 rows per block
  const int d = idx & 127;
  float h = hraw[idx];
  float hn = __fadd_rn(__fmul_rn(__fmul_rn(__fsub_rn(h, meanv[d]), rsv[d]), gamma[d]), beta[d]);
  float o = (hn >= 0.0f) ? hn : __fmul_rn(0.01f, hn);
  hfin[idx] = o;
  hb[idx] = f2bf(o);
  red[t] = o * o;
  __syncthreads();
  for (int off = 64; off > 0; off >>= 1) {
    if ((t & 127) < off) red[t] += red[t + off];
    __syncthreads();
  }
  if ((t & 127) == 0) atomicMax((unsigned*)&norms[0], __float_as_uint(red[t]));
}

// ---------------- max item row-norm^2: 32 rows/block, 1 atomic/block -------
__global__ void k_anorm(const float* __restrict__ items, float* __restrict__ norms) {
  __shared__ float red[4];
  const int t = threadIdx.x;  // 256: 32 rows x 8 lanes
  int row = blockIdx.x * 32 + (t >> 3);  // grid 1563
  if (row > 49999) row = 49999;          // dup row: harmless for max
  const float4* p = (const float4*)(items + (size_t)row * 128 + (t & 7) * 16);
  float ss = 0.0f;
#pragma unroll
  for (int k = 0; k < 4; ++k) {
    float4 v = p[k];
    ss += v.x * v.x + v.y * v.y + v.z * v.z + v.w * v.w;
  }
  ss += __shfl_xor(ss, 1);  // sum 8-lane row group
  ss += __shfl_xor(ss, 2);
  ss += __shfl_xor(ss, 4);
  ss = fmaxf(ss, __shfl_xor(ss, 8));   // max across rows in wave
  ss = fmaxf(ss, __shfl_xor(ss, 16));
  ss = fmaxf(ss, __shfl_xor(ss, 32));
  if ((t & 63) == 0) red[t >> 6] = ss;
  __syncthreads();
  if (t == 0) {
    float mx = fmaxf(fmaxf(red[0], red[1]), fmaxf(red[2], red[3]));
    atomicMax((unsigned*)&norms[1], __float_as_uint(mx));
  }
}

// ---------------- V0 seed: per-row achieved max over j in [0,1024) ----------
__global__ __launch_bounds__(256, 4) void k_seed(const float* __restrict__ hfin,
                                                 const float* __restrict__ items,
                                                 float* __restrict__ V0) {
  __shared__ float red[4][256];
  const int t = threadIdx.x;
  const int rbase = blockIdx.x * 4;
  float best[4] = {-INFINITY, -INFINITY, -INFINITY, -INFINITY};
  for (int q = 0; q < 4; ++q) {
    const int j = t + 256 * q;
    float acc[4] = {0.0f, 0.0f, 0.0f, 0.0f};
    const float* ap = items + (size_t)j * 128;
    for (int km = 0; km < 8; ++km) {
#pragma unroll
      for (int e = 0; e < 4; ++e) {
        float4 a4 = *(const float4*)(ap + km * 16 + 4 * e);
#pragma unroll
        for (int p = 0; p < 4; ++p) {
          const float* hp = hfin + (rbase + p) * 128 + km * 16 + 4 * e;
          float4 h4 = *(const float4*)hp;  // uniform -> s_load
          acc[p] = fmaf(h4.x, a4.x, acc[p]);
          acc[p] = fmaf(h4.y, a4.y, acc[p]);
          acc[p] = fmaf(h4.z, a4.z, acc[p]);
          acc[p] = fmaf(h4.w, a4.w, acc[p]);
        }
      }
    }
#pragma unroll
    for (int p = 0; p < 4; ++p) {
      unsigned l = (unsigned)(rbase + p) * 50000u + (unsigned)j;
      float g = gumbel_from_bits(tf2x32_xor(0u, l));
      best[p] = fmaxf(best[p], acc[p] + g);
    }
  }
#pragma unroll
  for (int p = 0; p < 4; ++p) red[p][t] = best[p];
  __syncthreads();
  for (int off = 128; off > 0; off >>= 1) {
    if (t < off) {
#pragma unroll
      for (int p = 0; p < 4; ++p) red[p][t] = fmaxf(red[p][t], red[p][t + off]);
    }
    __syncthreads();
  }
  if (t < 4) V0[rbase + t] = red[t][0];
}

// ---------------- bf16 MFMA screen, variant A: async-DMA staging -----------
// Round 11 shell, ONE delta: staging via 2 x global_load_lds(16B)/wave from
// PRE-CONVERTED bf16 items (ib). XOR swizzle moved to the per-lane GLOBAL
// source address (linear LDS dest = wave base + lane*16; XOR is an
// involution so src offset = col ^ ((ldsrow&7)<<4)). Kills ~200 VALU/iter
// of f2bf/pk2 + the f0..f3 register prefetch + swizzled-store conflicts.
// Ragged tail: clamp only the GLOBAL row (swizzle uses the LDS row).
__global__ __launch_bounds__(256, 2) void k_screen_dma(
    const unsigned short* __restrict__ hb, const float* __restrict__ hfin,
    const float* __restrict__ items, const unsigned short* __restrict__ ib,
    const float* __restrict__ V0,
    const float* __restrict__ norms, unsigned long long* __restrict__ rowslot) {
  __shared__ __align__(16) unsigned short Bs[2][32 * 128];  // 2 x 8KB swizzled
  __shared__ unsigned qk[4][128];  // per-wave candidate queues
  __shared__ float qsh[4][128];

  const int t = threadIdx.x;
  const int w = t >> 6, l = t & 63;
  const int lg = l >> 4, lr = l & 15;
  const int rg = blockIdx.x >> 6;
  const int span = blockIdx.x & 63;
  const int r0 = rg * 128;
  const int r0w = r0 + w * 32;
  const int tile0 = span * TPB;
  int nt = NTILES - tile0;
  nt = nt < 0 ? 0 : (nt > TPB ? TPB : nt);
  if (nt == 0) return;  // block-uniform (span 63)

  const float ERRC = 0.004f * sqrtf(norms[0] * norms[1]) + 0.01f;
  const volatile unsigned* hiw = (const volatile unsigned*)rowslot;  // hi @ 2R+1

  // resident A fragments: lane holds row (r0w + rt*16 + lr), 8 k each
  const unsigned short* aB0 = hb + (size_t)(r0w + lr) * 128 + lg * 8;
  bf16x8 Afrag[2][4];
#pragma unroll
  for (int kb = 0; kb < 4; ++kb) {
    Afrag[0][kb] = *(const bf16x8*)(aB0 + kb * 32);
    Afrag[1][kb] = *(const bf16x8*)(aB0 + 16 * 128 + kb * 32);
  }

  // staging: lane covers linear LDS offset o = w*2048 + l*16 (and +1024);
  // global src = ib + clamped_row*256 + (col ^ ((ldsrow&7)<<4)).
  const int o0 = w * 2048 + l * 16;
  const int row0 = o0 >> 8, col0 = o0 & 255;
  const int o1 = o0 + 1024;
  const int row1 = o1 >> 8, col1 = o1 & 255;
  const int sc0 = col0 ^ ((row0 & 7) << 4);
  const int sc1 = col1 ^ ((row1 & 7) << 4);

#define STAGE_TILE(tl, buf)                                                    \
  {                                                                            \
    const int Jg0 = min((tl) * 32 + row0, 49999);                              \
    const int Jg1 = min((tl) * 32 + row1, 49999);                              \
    __builtin_amdgcn_global_load_lds(                                          \
        (const unsigned int*)((const char*)ib + (size_t)Jg0 * 256 + sc0),      \
        (unsigned int*)((char*)Bs[buf] + w * 2048), 16, 0, 0);                 \
    __builtin_amdgcn_global_load_lds(                                          \
        (const unsigned int*)((const char*)ib + (size_t)Jg1 * 256 + sc1),      \
        (unsigned int*)((char*)Bs[buf] + w * 2048 + 1024), 16, 0, 0);          \
  }

  // prologue: stage tile0 -> Bs[0]
  STAGE_TILE(tile0, 0)
  __syncthreads();  // drains vmcnt -> Bs[0] ready

  const unsigned long long lml = (1ull << l) - 1ull;  // lanes below me
  unsigned qn = 0;     // wave-uniform queue count (SGPR)
  float th1[2][4];     // tier-1 thresholds, in registers

  int pb = 0;
  for (int it = 0; it < nt; ++it) {
    const int j0 = (tile0 + it) * 32;

    // ---- issue async stage of tile it+1 -> Bs[pb^1] (lands by barrier) ----
    if (it + 1 < nt) STAGE_TILE(tile0 + it + 1, pb ^ 1)

    // ---- refresh tier-1 thresholds every 4 tiles (stale-low is safe) ----
    if ((it & 3) == 0) {
#pragma unroll
      for (int rt = 0; rt < 2; ++rt)
#pragma unroll
        for (int q = 0; q < 4; ++q) {
          const int R = r0w + rt * 16 + lg * 4 + q;
          const unsigned hi = hiw[2 * R + 1];
          float tv = V0[R];
          if (hi) tv = fmaxf(tv, unordf(hi));
          th1[rt][q] = tv - GMAX - ERRC;
        }
    }

    // ---- MFMA from Bs[pb] ----
    f32x4 acc[2][2];
#pragma unroll
    for (int rt = 0; rt < 2; ++rt)
#pragma unroll
      for (int jt = 0; jt < 2; ++jt) acc[rt][jt] = (f32x4){0.f, 0.f, 0.f, 0.f};

#pragma unroll
    for (int kb = 0; kb < 4; ++kb) {
#pragma unroll
      for (int jt = 0; jt < 2; ++jt) {
        const int byte = (jt * 16 + lr) * 256 + kb * 64 + lg * 16;
        bf16x8 bfrag = *(const bf16x8*)((char*)Bs[pb] + bswz(byte));
        acc[0][jt] = __builtin_amdgcn_mfma_f32_16x16x32_bf16(Afrag[0][kb], bfrag, acc[0][jt], 0, 0, 0);
        acc[1][jt] = __builtin_amdgcn_mfma_f32_16x16x32_bf16(Afrag[1][kb], bfrag, acc[1][jt], 0, 0, 0);
      }
    }

    // ---- tier-1 push via ballot compaction; per-wave drain at >=64 ----
    // C/D layout: col = lane&15 (lr), row = (lane>>4)*4 + q.
#pragma unroll
    for (int rt = 0; rt < 2; ++rt)
#pragma unroll
      for (int q = 0; q < 4; ++q) {
        const float th = th1[rt][q];
#pragma unroll
        for (int jt = 0; jt < 2; ++jt) {
          const float s = acc[rt][jt][q];
          const int J = j0 + jt * 16 + lr;
          const bool c = (J < 50000) && (s >= th);
          const unsigned long long m = __ballot(c);
          if (m) {
            if (c) {
              const unsigned idx = qn + (unsigned)__popcll(m & lml);
              qk[w][idx] = ((unsigned)(rt * 16 + lg * 4 + q) << 16) | (unsigned)J;
              qsh[w][idx] = s;
            }
            qn += (unsigned)__popcll(m);
            if (qn >= 64) {  // drain fully (qn <= 127 -> fits cap 128)
              for (unsigned i = (unsigned)l; i < qn; i += 64) {
                const unsigned key = qk[w][i];
                resolve_cand(r0w + (int)(key >> 16), (int)(key & 0xFFFFu),
                             qsh[w][i], ERRC, hfin, items, V0, rowslot, hiw);
              }
              qn = 0;
            }
          }
        }
      }

    __syncthreads();  // drains vmcnt: Bs[pb^1] landed; Bs[pb] reads done
    pb ^= 1;
  }

  // ---- final drain ----
  for (unsigned i = (unsigned)l; i < qn; i += 64) {
    const unsigned key = qk[w][i];
    resolve_cand(r0w + (int)(key >> 16), (int)(key & 0xFFFFu),
                 qsh[w][i], ERRC, hfin, items, V0, rowslot, hiw);
  }
#undef STAGE_TILE
}

// ---------------- variant B: register-staged (round 11, proven 238us) ------
// Used when ws_size cannot hold the 12.8MB pre-converted ib buffer.
__global__ __launch_bounds__(256, 2) void k_screen_reg(
    const unsigned short* __restrict__ hb, const float* __restrict__ hfin,
    const float* __restrict__ items, const float* __restrict__ V0,
    const float* __restrict__ norms, unsigned long long* __restrict__ rowslot) {
  __shared__ __align__(16) unsigned short Bs[2][32 * 128];  // 2 x 8KB swizzled
  __shared__ unsigned qk[4][128];
  __shared__ float qsh[4][128];

  const int t = threadIdx.x;
  const int w = t >> 6, l = t & 63;
  const int lg = l >> 4, lr = l & 15;
  const int rg = blockIdx.x >> 6;
  const int span = blockIdx.x & 63;
  const int r0 = rg * 128;
  const int r0w = r0 + w * 32;
  const int tile0 = span * TPB;
  int nt = NTILES - tile0;
  nt = nt < 0 ? 0 : (nt > TPB ? TPB : nt);
  if (nt == 0) return;

  const float ERRC = 0.004f * sqrtf(norms[0] * norms[1]) + 0.01f;
  const volatile unsigned* hiw = (const volatile unsigned*)rowslot;

  const unsigned short* aB0 = hb + (size_t)(r0w + lr) * 128 + lg * 8;
  bf16x8 Afrag[2][4];
#pragma unroll
  for (int kb = 0; kb < 4; ++kb) {
    Afrag[0][kb] = *(const bf16x8*)(aB0 + kb * 32);
    Afrag[1][kb] = *(const bf16x8*)(aB0 + 16 * 128 + kb * 32);
  }

  const int jl = t >> 3;
  const int c0 = (t & 7) * 16;
  float4 f0, f1, f2, f3;

  {
    const int Jg = min(tile0 * 32 + jl, 49999);
    const float4* src = (const float4*)(items + (size_t)Jg * 128 + c0);
    f0 = src[0]; f1 = src[1]; f2 = src[2]; f3 = src[3];
    uint4 A, B;
    A.x = pk2(f0.x, f0.y); A.y = pk2(f0.z, f0.w);
    A.z = pk2(f1.x, f1.y); A.w = pk2(f1.z, f1.w);
    B.x = pk2(f2.x, f2.y); B.y = pk2(f2.z, f2.w);
    B.z = pk2(f3.x, f3.y); B.w = pk2(f3.z, f3.w);
    const int byte0 = jl * 256 + c0 * 2;
    *(uint4*)((char*)Bs[0] + bswz(byte0)) = A;
    *(uint4*)((char*)Bs[0] + bswz(byte0 + 16)) = B;
  }
  if (nt > 1) {
    const int Jg = min((tile0 + 1) * 32 + jl, 49999);
    const float4* src = (const float4*)(items + (size_t)Jg * 128 + c0);
    f0 = src[0]; f1 = src[1]; f2 = src[2]; f3 = src[3];
  }
  __syncthreads();

  const unsigned long long lml = (1ull << l) - 1ull;
  unsigned qn = 0;
  float th1[2][4];

  int pb = 0;
  for (int it = 0; it < nt; ++it) {
    const int j0 = (tile0 + it) * 32;

    if ((it & 3) == 0) {
#pragma unroll
      for (int rt = 0; rt < 2; ++rt)
#pragma unroll
        for (int q = 0; q < 4; ++q) {
          const int R = r0w + rt * 16 + lg * 4 + q;
          const unsigned hi = hiw[2 * R + 1];
          float tv = V0[R];
          if (hi) tv = fmaxf(tv, unordf(hi));
          th1[rt][q] = tv - GMAX - ERRC;
        }
    }

    if (it + 1 < nt) {
      uint4 A, B;
      A.x = pk2(f0.x, f0.y); A.y = pk2(f0.z, f0.w);
      A.z = pk2(f1.x, f1.y); A.w = pk2(f1.z, f1.w);
      B.x = pk2(f2.x, f2.y); B.y = pk2(f2.z, f2.w);
      B.z = pk2(f3.x, f3.y); B.w = pk2(f3.z, f3.w);
      const int byte0 = jl * 256 + c0 * 2;
      *(uint4*)((char*)Bs[pb ^ 1] + bswz(byte0)) = A;
      *(uint4*)((char*)Bs[pb ^ 1] + bswz(byte0 + 16)) = B;
    }
    if (it + 2 < nt) {
      const int Jg = min((tile0 + it + 2) * 32 + jl, 49999);
      const float4* src = (const float4*)(items + (size_t)Jg * 128 + c0);
      f0 = src[0]; f1 = src[1]; f2 = src[2]; f3 = src[3];
    }

    f32x4 acc[2][2];
#pragma unroll
    for (int rt = 0; rt < 2; ++rt)
#pragma unroll
      for (int jt = 0; jt < 2; ++jt) acc[rt][jt] = (f32x4){0.f, 0.f, 0.f, 0.f};

#pragma unroll
    for (int kb = 0; kb < 4; ++kb) {
#pragma unroll
      for (int jt = 0; jt < 2; ++jt) {
        const int byte = (jt * 16 + lr) * 256 + kb * 64 + lg * 16;
        bf16x8 bfrag = *(const bf16x8*)((char*)Bs[pb] + bswz(byte));
        acc[0][jt] = __builtin_amdgcn_mfma_f32_16x16x32_bf16(Afrag[0][kb], bfrag, acc[0][jt], 0, 0, 0);
        acc[1][jt] = __builtin_amdgcn_mfma_f32_16x16x32_bf16(Afrag[1][kb], bfrag, acc[1][jt], 0, 0, 0);
      }
    }

#pragma unroll
    for (int rt = 0; rt < 2; ++rt)
#pragma unroll
      for (int q = 0; q < 4; ++q) {
        const float th = th1[rt][q];
#pragma unroll
        for (int jt = 0; jt < 2; ++jt) {
          const float s = acc[rt][jt][q];
          const int J = j0 + jt * 16 + lr;
          const bool c = (J < 50000) && (s >= th);
          const unsigned long long m = __ballot(c);
          if (m) {
            if (c) {
              const unsigned idx = qn + (unsigned)__popcll(m & lml);
              qk[w][idx] = ((unsigned)(rt * 16 + lg * 4 + q) << 16) | (unsigned)J;
              qsh[w][idx] = s;
            }
            qn += (unsigned)__popcll(m);
            if (qn >= 64) {
              for (unsigned i = (unsigned)l; i < qn; i += 64) {
                const unsigned key = qk[w][i];
                resolve_cand(r0w + (int)(key >> 16), (int)(key & 0xFFFFu),
                             qsh[w][i], ERRC, hfin, items, V0, rowslot, hiw);
              }
              qn = 0;
            }
          }
        }
      }

    __syncthreads();
    pb ^= 1;
  }

  for (unsigned i = (unsigned)l; i < qn; i += 64) {
    const unsigned key = qk[w][i];
    resolve_cand(r0w + (int)(key >> 16), (int)(key & 0xFFFFu),
                 qsh[w][i], ERRC, hfin, items, V0, rowslot, hiw);
  }
}

// ---------------- final: read row winner + cosine sim (one wave/row) -------
__global__ void k_final(const unsigned long long* __restrict__ rowslot,
                        const int* __restrict__ uid, const float* __restrict__ items,
                        float* __restrict__ dout, float* __restrict__ simv) {
  const int r = blockIdx.x;
  const int lane = threadIdx.x;  // 64
  const unsigned long long pk = rowslot[r];  // nonzero: winner always pushed
  const int bi = (int)(0xFFFFFFFFu - (unsigned)pk);
  if (lane == 0) dout[r] = (float)bi;

  const int orig = uid[r * 2 + 1];
  float o1 = items[(size_t)orig * 128 + lane];
  float o2 = items[(size_t)orig * 128 + 64 + lane];
  float p1 = items[(size_t)bi * 128 + lane];
  float p2 = items[(size_t)bi * 128 + 64 + lane];
  float d = o1 * p1 + o2 * p2;
  float s1 = o1 * o1 + o2 * o2;
  float s2 = p1 * p1 + p2 * p2;
  for (int off = 32; off > 0; off >>= 1) {
    d += __shfl_down(d, off);
    s1 += __shfl_down(s1, off);
    s2 += __shfl_down(s2, off);
  }
  if (lane == 0) {
    float n1 = fmaxf(sqrtf(s1), 1e-6f);
    float n2 = fmaxf(sqrtf(s2), 1e-6f);
    float sim = d / (n1 * n2);
    simv[r] = (sim + 1.0f) * 0.5f;
  }
}

// ---------------- final scalar reductions ----------------
__global__ void k_reduce(const float* __restrict__ simv, float* __restrict__ dout) {
  __shared__ double rl[256];
  __shared__ double rs[256];
  const int t = threadIdx.x;
  double L = 0.0, S = 0.0;
  for (int i = t; i < 2048; i += 256) {
    double s = (double)simv[i];
    double dd = s - 0.5;
    L += dd * dd;
    S += s;
  }
  rl[t] = L; rs[t] = S;
  __syncthreads();
  for (int off = 128; off > 0; off >>= 1) {
    if (t < off) { rl[t] += rl[t + off]; rs[t] += rs[t + off]; }
    __syncthreads();
  }
  if (t == 0) {
    dout[2048] = (float)(rl[0] * (1.0 / 2048.0));
    dout[2049] = (float)(rs[0] * (1.0 / 2048.0));
  }
}

extern "C" void kernel_launch(void* const* d_in, const int* in_sizes, int n_in,
                              void* d_out, int out_size, void* d_ws, size_t ws_size,
                              hipStream_t stream) {
  const int* uid = (const int*)d_in[0];       // (2048,2) int32
  const float* xfeat = (const float*)d_in[1]; // (2048,256)
  const float* items = (const float*)d_in[2]; // (50000,128)
  const float* W = (const float*)d_in[3];     // (256,128)
  const float* bias = (const float*)d_in[4];  // (128,)
  const float* gamma = (const float*)d_in[5]; // (128,)
  const float* beta = (const float*)d_in[6];  // (128,)

  float* ws = (float*)d_ws;
  float* hraw = ws;                                   // 262144 f
  float* hfin = ws + 262144;                          // 262144 f
  float* meanv = ws + 524288;                         // 128 f
  float* rsv = ws + 524416;                           // 128 f
  float* V0 = ws + 524544;                            // 2048 f
  float* simv = ws + 526592;                          // 2048 f
  float* norms = ws + 528640;                         // 2 f (Hmax^2, Amax^2)
  unsigned long long* rowslot =
      (unsigned long long*)(ws + 528642);             // 2048 u64 (8B aligned)
  unsigned short* hb = (unsigned short*)(ws + 532740); // 262144 bf16
  unsigned short* ib = (unsigned short*)(ws + 663812); // 12.8MB bf16 (16B aligned)
  float* dout = (float*)d_out;                        // 2050 floats

  // ib ends at byte 663812*4 + 12,800,000 = 15,455,248
  const bool big_ws = ws_size >= (size_t)15455248;

  if (big_ws)
    hipLaunchKernelGGL(k_bconv, dim3(3125), dim3(256), 0, stream, items, ib);
  hipLaunchKernelGGL(k_hraw, dim3(2048), dim3(128), 0, stream, xfeat, W, bias, hraw, rowslot, norms);
  hipLaunchKernelGGL(k_bnstats, dim3(128), dim3(256), 0, stream, hraw, meanv, rsv);
  hipLaunchKernelGGL(k_apply, dim3(1024), dim3(256), 0, stream, hraw, meanv, rsv, gamma, beta, hfin, hb, norms);
  hipLaunchKernelGGL(k_anorm, dim3(1563), dim3(256), 0, stream, items, norms);
  hipLaunchKernelGGL(k_seed, dim3(512), dim3(256), 0, stream, hfin, items, V0);
  if (big_ws)
    hipLaunchKernelGGL(k_screen_dma, dim3(1024), dim3(256), 0, stream, hb, hfin, items, ib, V0, norms, rowslot);
  else
    hipLaunchKernelGGL(k_screen_reg, dim3(1024), dim3(256), 0, stream, hb, hfin, items, V0, norms, rowslot);
  hipLaunchKernelGGL(k_final, dim3(2048), dim3(64), 0, stream, rowslot, uid, items, dout, simv);
  hipLaunchKernelGGL(k_reduce, dim3(1), dim3(256), 0, stream, simv, dout);
}

// Round 14
// 407.241 us; speedup vs baseline: 1.0127x; 1.0127x over previous
//
#include <hip/hip_runtime.h>
#include <math.h>

#define TINYF 1.17549435e-38f
#define GMAX 16.0f   // hard upper bound on gumbel (15.9424) + slack
#define NTILES 1563  // ceil(50000/32)
#define TPB 25       // tiles per span (64 spans x 25 >= 1563)

typedef __attribute__((ext_vector_type(8))) short bf16x8;
typedef __attribute__((ext_vector_type(4))) float f32x4;

// ---------------- threefry2x32, key = (0, 42) ----------------
__device__ __forceinline__ unsigned rotl32(unsigned x, int r) {
  return (x << r) | (x >> (32 - r));
}

__device__ __forceinline__ unsigned tf2x32_xor(unsigned x0, unsigned x1) {
  const unsigned k0 = 0u, k1 = 42u, k2 = 0x1BD11BF0u;  // 0x1BD11BDA ^ 0 ^ 42
  x0 += k0; x1 += k1;
#define TFR(r) { x0 += x1; x1 = rotl32(x1, r); x1 ^= x0; }
  TFR(13) TFR(15) TFR(26) TFR(6)
  x0 += k1; x1 += k2 + 1u;
  TFR(17) TFR(29) TFR(16) TFR(24)
  x0 += k2; x1 += k0 + 2u;
  TFR(13) TFR(15) TFR(26) TFR(6)
  x0 += k0; x1 += k1 + 3u;
  TFR(17) TFR(29) TFR(16) TFR(24)
  x0 += k1; x1 += k2 + 4u;
  TFR(13) TFR(15) TFR(26) TFR(6)
  x0 += k2; x1 += k0 + 5u;
#undef TFR
  return x0 ^ x1;
}

__device__ __forceinline__ float gumbel_from_bits(unsigned bits) {
  float f = __uint_as_float((bits >> 9) | 0x3f800000u) - 1.0f;
  float u = fmaxf(f, TINYF);
  return -logf(-logf(u));
}

// order-preserving float->uint (monotone)
__device__ __forceinline__ unsigned ordf(float v) {
  unsigned b = __float_as_uint(v);
  return (b & 0x80000000u) ? ~b : (b | 0x80000000u);
}
__device__ __forceinline__ float unordf(unsigned u) {
  unsigned b = (u & 0x80000000u) ? (u & 0x7FFFFFFFu) : ~u;
  return __uint_as_float(b);
}

// fp32 -> bf16 RNE (bit trick)
__device__ __forceinline__ unsigned short f2bf(float f) {
  unsigned u = __float_as_uint(f);
  unsigned r = u + 0x7FFFu + ((u >> 16) & 1u);
  return (unsigned short)(r >> 16);
}
__device__ __forceinline__ unsigned pk2(float a, float b) {
  return (unsigned)f2bf(a) | ((unsigned)f2bf(b) << 16);
}
// LDS XOR swizzle for 256B-row tile (breaks 32-way ds_read_b128 conflict)
__device__ __forceinline__ int bswz(int b) { return b ^ (((b >> 8) & 7) << 4); }

// ---- candidate resolution. Fresh tier-2 threshold from rowslot (tighter,
// still sound). Fast u-space pre-test with HW exp (no false reject, ~2e-5
// over-accept filtered by the exact path). ONE noinline copy, dense drains.
__device__ __attribute__((noinline)) void resolve_cand(
    int R, int J, float s, float ERRC,
    const float* __restrict__ hfin, const float* __restrict__ items,
    const float* __restrict__ V0,
    unsigned long long* __restrict__ rowslot, const volatile unsigned* hiw) {
  const unsigned hi0 = hiw[2 * R + 1];
  float tv = V0[R];
  if (hi0) tv = fmaxf(tv, unordf(hi0));
  const float thr2 = tv - ERRC;  // sound: s_fp32 + g <= s_bf16 + ERRC + g
  const float d = thr2 - s;
  const unsigned bits = tf2x32_xor(0u, (unsigned)R * 50000u + (unsigned)J);
  const float f = __uint_as_float((bits >> 9) | 0x3f800000u) - 1.0f;
  const float u = fmaxf(f, TINYF);
  const float thr_u = __expf(-__expf(-d)) * (1.0f - 2e-5f);
  if (u < thr_u) return;             // sound fast reject
  const float g = -logf(-logf(u));   // exact gumbel (rare path)
  if (s + g < thr2) return;          // exact tier-2
  const float4* hp = (const float4*)(hfin + (size_t)R * 128);
  const float4* ap = (const float4*)(items + (size_t)J * 128);
  float4 a4 = {0.f, 0.f, 0.f, 0.f};
#pragma unroll
  for (int k = 0; k < 32; ++k) {
    float4 h = hp[k];
    float4 b = ap[k];
    a4.x = fmaf(h.x, b.x, a4.x);
    a4.y = fmaf(h.y, b.y, a4.y);
    a4.z = fmaf(h.z, b.z, a4.z);
    a4.w = fmaf(h.w, b.w, a4.w);
  }
  const float v = ((a4.x + a4.y) + (a4.z + a4.w)) + g;
  const unsigned ov = ordf(v);
  if (ov >= hiw[2 * R + 1]) {  // '>=': let atomicMax resolve smaller-J ties
    const unsigned long long pk =
        ((unsigned long long)ov << 32) | (0xFFFFFFFFu - (unsigned)J);
    atomicMax(&rowslot[R], pk);
  }
}

// ---------------- h = x @ W + b (f64 accumulate) + workspace init ----------
__global__ void k_hraw(const float* __restrict__ x, const float* __restrict__ W,
                       const float* __restrict__ b, float* __restrict__ hraw,
                       unsigned long long* __restrict__ rowslot,
                       float* __restrict__ norms) {
  __shared__ float sx[256];
  const int i = blockIdx.x;
  const int d = threadIdx.x;  // 128 threads
  if (d == 0) {
    rowslot[i] = 0ull;
    if (i == 0) { norms[0] = 0.0f; norms[1] = 0.0f; }
  }
  sx[d] = x[i * 256 + d];
  sx[d + 128] = x[i * 256 + 128 + d];
  __syncthreads();
  double acc = 0.0;
  for (int k = 0; k < 256; ++k)
    acc = fma((double)sx[k], (double)W[k * 128 + d], acc);
  hraw[i * 128 + d] = (float)acc + b[d];
}

// ---- items fp32 -> bf16 (RNE, same bits) + max row-norm^2, one pass -------
// grid 1563 x 256: 32 rows/block, 8 lanes/row x 16 cols. Launched AFTER
// k_hraw (stream order) so norms[1]=0 init precedes these atomics.
__global__ void k_bca(const float* __restrict__ items,
                      unsigned short* __restrict__ ib,
                      float* __restrict__ norms) {
  __shared__ float red[4];
  const int t = threadIdx.x;
  const int row = blockIdx.x * 32 + (t >> 3);
  const int rc = row > 49999 ? 49999 : row;  // dup row: harmless for max
  const int c = (t & 7) * 16;
  const float4* p = (const float4*)(items + (size_t)rc * 128 + c);
  const float4 v0 = p[0], v1 = p[1], v2 = p[2], v3 = p[3];
  float ss = v0.x * v0.x + v0.y * v0.y + v0.z * v0.z + v0.w * v0.w +
             v1.x * v1.x + v1.y * v1.y + v1.z * v1.z + v1.w * v1.w +
             v2.x * v2.x + v2.y * v2.y + v2.z * v2.z + v2.w * v2.w +
             v3.x * v3.x + v3.y * v3.y + v3.z * v3.z + v3.w * v3.w;
  if (row <= 49999) {
    uint4 o0, o1;
    o0.x = pk2(v0.x, v0.y); o0.y = pk2(v0.z, v0.w);
    o0.z = pk2(v1.x, v1.y); o0.w = pk2(v1.z, v1.w);
    o1.x = pk2(v2.x, v2.y); o1.y = pk2(v2.z, v2.w);
    o1.z = pk2(v3.x, v3.y); o1.w = pk2(v3.z, v3.w);
    uint4* dst = (uint4*)(ib + (size_t)row * 128 + c);
    dst[0] = o0; dst[1] = o1;
  }
  ss += __shfl_xor(ss, 1);  // sum 8-lane row group
  ss += __shfl_xor(ss, 2);
  ss += __shfl_xor(ss, 4);
  ss = fmaxf(ss, __shfl_xor(ss, 8));   // max across rows in wave
  ss = fmaxf(ss, __shfl_xor(ss, 16));
  ss = fmaxf(ss, __shfl_xor(ss, 32));
  if ((t & 63) == 0) red[t >> 6] = ss;
  __syncthreads();
  if (t == 0) {
    float mx = fmaxf(fmaxf(red[0], red[1]), fmaxf(red[2], red[3]));
    atomicMax((unsigned*)&norms[1], __float_as_uint(mx));
  }
}

// ---------------- BN stats per column (f64) ----------------
__global__ void k_bnstats(const float* __restrict__ hraw,
                          float* __restrict__ meanv, float* __restrict__ rsv) {
  __shared__ double red[256];
  const int d = blockIdx.x;   // 128 blocks
  const int t = threadIdx.x;  // 256 threads
  double s = 0.0;
  for (int i = t; i < 2048; i += 256) s += (double)hraw[i * 128 + d];
  red[t] = s;
  __syncthreads();
  for (int off = 128; off > 0; off >>= 1) {
    if (t < off) red[t] += red[t + off];
    __syncthreads();
  }
  const float m = (float)(red[0] * (1.0 / 2048.0));
  __syncthreads();
  double v = 0.0;
  for (int i = t; i < 2048; i += 256) {
    float dd = __fsub_rn(hraw[i * 128 + d], m);
    v += (double)dd * (double)dd;
  }
  red[t] = v;
  __syncthreads();
  for (int off = 128; off > 0; off >>= 1) {
    if (t < off) red[t] += red[t + off];
    __syncthreads();
  }
  if (t == 0) {
    float var = (float)(red[0] * (1.0 / 2048.0));
    float vpe = __fadd_rn(var, 1e-5f);
    meanv[d] = m;
    rsv[d] = (float)(1.0 / sqrt((double)vpe));
  }
}

// ---------------- apply BN + leaky relu, emit bf16 copy + max row-norm ------
__global__ void k_apply(const float* __restrict__ hraw,
                        const float* __restrict__ meanv, const float* __restrict__ rsv,
                        const float* __restrict__ gamma, const float* __restrict__ beta,
                        float* __restrict__ hfin, unsigned short* __restrict__ hb,
                        float* __restrict__ norms) {
  __shared__ float red[256];
  const int t = threadIdx.x;
  const int idx = blockIdx.x * 256 + t;  // 2 rows per block
  const int d = idx & 127;
  float h = hraw[idx];
  float hn = __fadd_rn(__fmul_rn(__fmul_rn(__fsub_rn(h, meanv[d]), rsv[d]), gamma[d]), beta[d]);
  float o = (hn >= 0.0f) ? hn : __fmul_rn(0.01f, hn);
  hfin[idx] = o;
  hb[idx] = f2bf(o);
  red[t] = o * o;
  __syncthreads();
  for (int off = 64; off > 0; off >>= 1) {
    if ((t & 127) < off) red[t] += red[t + off];
    __syncthreads();
  }
  if ((t & 127) == 0) atomicMax((unsigned*)&norms[0], __float_as_uint(red[t]));
}

// ---------------- V0 seed: per-row achieved max over j in [0,1024) ----------
__global__ __launch_bounds__(256, 4) void k_seed(const float* __restrict__ hfin,
                                                 const float* __restrict__ items,
                                                 float* __restrict__ V0) {
  __shared__ float red[4][256];
  const int t = threadIdx.x;
  const int rbase = blockIdx.x * 4;
  float best[4] = {-INFINITY, -INFINITY, -INFINITY, -INFINITY};
  for (int q = 0; q < 4; ++q) {
    const int j = t + 256 * q;
    float acc[4] = {0.0f, 0.0f, 0.0f, 0.0f};
    const float* ap = items + (size_t)j * 128;
    for (int km = 0; km < 8; ++km) {
#pragma unroll
      for (int e = 0; e < 4; ++e) {
        float4 a4 = *(const float4*)(ap + km * 16 + 4 * e);
#pragma unroll
        for (int p = 0; p < 4; ++p) {
          const float* hp = hfin + (rbase + p) * 128 + km * 16 + 4 * e;
          float4 h4 = *(const float4*)hp;  // uniform -> s_load
          acc[p] = fmaf(h4.x, a4.x, acc[p]);
          acc[p] = fmaf(h4.y, a4.y, acc[p]);
          acc[p] = fmaf(h4.z, a4.z, acc[p]);
          acc[p] = fmaf(h4.w, a4.w, acc[p]);
        }
      }
    }
#pragma unroll
    for (int p = 0; p < 4; ++p) {
      unsigned l = (unsigned)(rbase + p) * 50000u + (unsigned)j;
      float g = gumbel_from_bits(tf2x32_xor(0u, l));
      best[p] = fmaxf(best[p], acc[p] + g);
    }
  }
#pragma unroll
  for (int p = 0; p < 4; ++p) red[p][t] = best[p];
  __syncthreads();
  for (int off = 128; off > 0; off >>= 1) {
    if (t < off) {
#pragma unroll
      for (int p = 0; p < 4; ++p) red[p][t] = fmaxf(red[p][t], red[p][t + off]);
    }
    __syncthreads();
  }
  if (t < 4) V0[rbase + t] = red[t][0];
}

// ---------------- bf16 MFMA screen: 64-row blocks for occupancy ------------
// Round 13 structure with the row-tile HALVED: 64 rows/block (1 MFMA
// row-tile of 16 per wave), grid 2048 = 32 rg x 64 spans (bid&63 = span ->
// XCD-local j-window preserved). Live set drops ~40 VGPR (Afrag 32->16,
// acc 16->8) -> ~6 blocks/CU resident (was ~2) = 3x latency hiding; the
// rounds-9..13 plateau at ~230us was unhidden latency at 8 waves/CU.
// Threshold refresh: COALESCED lane<16 load of rowslot hi-words + V0,
// distributed via __shfl (was 8 scattered volatile dwords/thread); every
// iter (cheap now, and tighter pruning). DMA staging + ballot queues kept.
__global__ __launch_bounds__(256, 2) void k_screen(
    const unsigned short* __restrict__ hb, const float* __restrict__ hfin,
    const float* __restrict__ items, const unsigned short* __restrict__ ib,
    const float* __restrict__ V0,
    const float* __restrict__ norms, unsigned long long* __restrict__ rowslot) {
  __shared__ __align__(16) unsigned short Bs[2][32 * 128];  // 2 x 8KB swizzled
  __shared__ unsigned qk[4][128];  // per-wave candidate queues
  __shared__ float qsh[4][128];

  const int t = threadIdx.x;
  const int w = t >> 6, l = t & 63;
  const int lg = l >> 4, lr = l & 15;
  const int rg = blockIdx.x >> 6;       // 0..31
  const int span = blockIdx.x & 63;
  const int r0w = rg * 64 + w * 16;     // this wave's 16 rows
  const int tile0 = span * TPB;
  int nt = NTILES - tile0;
  nt = nt < 0 ? 0 : (nt > TPB ? TPB : nt);
  if (nt == 0) return;  // block-uniform (span 63)

  const float ERRC = 0.004f * sqrtf(norms[0] * norms[1]) + 0.01f;
  const volatile unsigned* hiw = (const volatile unsigned*)rowslot;  // hi @ 2R+1

  // resident A fragments: lane holds row (r0w + lr), 8 k each
  const unsigned short* aB0 = hb + (size_t)(r0w + lr) * 128 + lg * 8;
  bf16x8 Afrag[4];
#pragma unroll
  for (int kb = 0; kb < 4; ++kb) Afrag[kb] = *(const bf16x8*)(aB0 + kb * 32);

  // staging: lane covers linear LDS offset o = w*2048 + l*16 (and +1024);
  // global src = ib + clamped_row*256 + (col ^ ((ldsrow&7)<<4)).
  const int o0 = w * 2048 + l * 16;
  const int row0 = o0 >> 8, col0 = o0 & 255;
  const int o1 = o0 + 1024;
  const int row1 = o1 >> 8, col1 = o1 & 255;
  const int sc0 = col0 ^ ((row0 & 7) << 4);
  const int sc1 = col1 ^ ((row1 & 7) << 4);

#define STAGE_TILE(tl, buf)                                                    \
  {                                                                            \
    const int Jg0 = min((tl) * 32 + row0, 49999);                              \
    const int Jg1 = min((tl) * 32 + row1, 49999);                              \
    __builtin_amdgcn_global_load_lds(                                          \
        (const unsigned int*)((const char*)ib + (size_t)Jg0 * 256 + sc0),      \
        (unsigned int*)((char*)Bs[buf] + w * 2048), 16, 0, 0);                 \
    __builtin_amdgcn_global_load_lds(                                          \
        (const unsigned int*)((const char*)ib + (size_t)Jg1 * 256 + sc1),      \
        (unsigned int*)((char*)Bs[buf] + w * 2048 + 1024), 16, 0, 0);          \
  }

  // prologue: stage tile0 -> Bs[0]
  STAGE_TILE(tile0, 0)
  __syncthreads();  // drains vmcnt -> Bs[0] ready

  const unsigned long long lml = (1ull << l) - 1ull;  // lanes below me
  unsigned qn = 0;     // wave-uniform queue count (SGPR)

  int pb = 0;
  for (int it = 0; it < nt; ++it) {
    const int j0 = (tile0 + it) * 32;

    // ---- issue async stage of tile it+1 -> Bs[pb^1] (lands by barrier) ----
    if (it + 1 < nt) STAGE_TILE(tile0 + it + 1, pb ^ 1)

    // ---- tier-1 thresholds: coalesced lane<16 load + shfl distribute ----
    // stale-low reads are monotone-safe; refreshed every iter (cheap).
    float tvl = 0.0f;
    if (l < 16) {
      const int R = r0w + l;
      const unsigned hi = hiw[2 * R + 1];
      tvl = V0[R];
      if (hi) tvl = fmaxf(tvl, unordf(hi));
    }
    float th1[4];
#pragma unroll
    for (int q = 0; q < 4; ++q)
      th1[q] = __shfl(tvl, lg * 4 + q) - GMAX - ERRC;

    // ---- MFMA from Bs[pb] ----
    f32x4 acc[2];
    acc[0] = (f32x4){0.f, 0.f, 0.f, 0.f};
    acc[1] = (f32x4){0.f, 0.f, 0.f, 0.f};
#pragma unroll
    for (int kb = 0; kb < 4; ++kb) {
#pragma unroll
      for (int jt = 0; jt < 2; ++jt) {
        const int byte = (jt * 16 + lr) * 256 + kb * 64 + lg * 16;
        bf16x8 bfrag = *(const bf16x8*)((char*)Bs[pb] + bswz(byte));
        acc[jt] = __builtin_amdgcn_mfma_f32_16x16x32_bf16(Afrag[kb], bfrag, acc[jt], 0, 0, 0);
      }
    }

    // ---- tier-1 push via ballot compaction; per-wave drain at >=64 ----
    // C/D layout: col = lane&15 (lr), row = (lane>>4)*4 + q.
#pragma unroll
    for (int q = 0; q < 4; ++q) {
      const float th = th1[q];
#pragma unroll
      for (int jt = 0; jt < 2; ++jt) {
        const float s = acc[jt][q];
        const int J = j0 + jt * 16 + lr;
        const bool c = (J < 50000) && (s >= th);
        const unsigned long long m = __ballot(c);
        if (m) {
          if (c) {
            const unsigned idx = qn + (unsigned)__popcll(m & lml);
            qk[w][idx] = ((unsigned)(lg * 4 + q) << 16) | (unsigned)J;
            qsh[w][idx] = s;
          }
          qn += (unsigned)__popcll(m);
          if (qn >= 64) {  // drain fully (qn <= 127 -> fits cap 128)
            for (unsigned i = (unsigned)l; i < qn; i += 64) {
              const unsigned key = qk[w][i];
              resolve_cand(r0w + (int)(key >> 16), (int)(key & 0xFFFFu),
                           qsh[w][i], ERRC, hfin, items, V0, rowslot, hiw);
            }
            qn = 0;
          }
        }
      }
    }

    __syncthreads();  // drains vmcnt: Bs[pb^1] landed; Bs[pb] reads done
    pb ^= 1;
  }

  // ---- final drain ----
  for (unsigned i = (unsigned)l; i < qn; i += 64) {
    const unsigned key = qk[w][i];
    resolve_cand(r0w + (int)(key >> 16), (int)(key & 0xFFFFu),
                 qsh[w][i], ERRC, hfin, items, V0, rowslot, hiw);
  }
#undef STAGE_TILE
}

// ---------------- final: read row winner + cosine sim (one wave/row) -------
__global__ void k_final(const unsigned long long* __restrict__ rowslot,
                        const int* __restrict__ uid, const float* __restrict__ items,
                        float* __restrict__ dout, float* __restrict__ simv) {
  const int r = blockIdx.x;
  const int lane = threadIdx.x;  // 64
  const unsigned long long pk = rowslot[r];  // nonzero: winner always pushed
  const int bi = (int)(0xFFFFFFFFu - (unsigned)pk);
  if (lane == 0) dout[r] = (float)bi;

  const int orig = uid[r * 2 + 1];
  float o1 = items[(size_t)orig * 128 + lane];
  float o2 = items[(size_t)orig * 128 + 64 + lane];
  float p1 = items[(size_t)bi * 128 + lane];
  float p2 = items[(size_t)bi * 128 + 64 + lane];
  float d = o1 * p1 + o2 * p2;
  float s1 = o1 * o1 + o2 * o2;
  float s2 = p1 * p1 + p2 * p2;
  for (int off = 32; off > 0; off >>= 1) {
    d += __shfl_down(d, off);
    s1 += __shfl_down(s1, off);
    s2 += __shfl_down(s2, off);
  }
  if (lane == 0) {
    float n1 = fmaxf(sqrtf(s1), 1e-6f);
    float n2 = fmaxf(sqrtf(s2), 1e-6f);
    float sim = d / (n1 * n2);
    simv[r] = (sim + 1.0f) * 0.5f;
  }
}

// ---------------- final scalar reductions ----------------
__global__ void k_reduce(const float* __restrict__ simv, float* __restrict__ dout) {
  __shared__ double rl[256];
  __shared__ double rs[256];
  const int t = threadIdx.x;
  double L = 0.0, S = 0.0;
  for (int i = t; i < 2048; i += 256) {
    double s = (double)simv[i];
    double dd = s - 0.5;
    L += dd * dd;
    S += s;
  }
  rl[t] = L; rs[t] = S;
  __syncthreads();
  for (int off = 128; off > 0; off >>= 1) {
    if (t < off) { rl[t] += rl[t + off]; rs[t] += rs[t + off]; }
    __syncthreads();
  }
  if (t == 0) {
    dout[2048] = (float)(rl[0] * (1.0 / 2048.0));
    dout[2049] = (float)(rs[0] * (1.0 / 2048.0));
  }
}

extern "C" void kernel_launch(void* const* d_in, const int* in_sizes, int n_in,
                              void* d_out, int out_size, void* d_ws, size_t ws_size,
                              hipStream_t stream) {
  const int* uid = (const int*)d_in[0];       // (2048,2) int32
  const float* xfeat = (const float*)d_in[1]; // (2048,256)
  const float* items = (const float*)d_in[2]; // (50000,128)
  const float* W = (const float*)d_in[3];     // (256,128)
  const float* bias = (const float*)d_in[4];  // (128,)
  const float* gamma = (const float*)d_in[5]; // (128,)
  const float* beta = (const float*)d_in[6];  // (128,)

  float* ws = (float*)d_ws;
  float* hraw = ws;                                   // 262144 f
  float* hfin = ws + 262144;                          // 262144 f
  float* meanv = ws + 524288;                         // 128 f
  float* rsv = ws + 524416;                           // 128 f
  float* V0 = ws + 524544;                            // 2048 f
  float* simv = ws + 526592;                          // 2048 f
  float* norms = ws + 528640;                         // 2 f (Hmax^2, Amax^2)
  unsigned long long* rowslot =
      (unsigned long long*)(ws + 528642);             // 2048 u64 (8B aligned)
  unsigned short* hb = (unsigned short*)(ws + 532740); // 262144 bf16
  unsigned short* ib = (unsigned short*)(ws + 663812); // 12.8MB bf16 (16B aligned)
  float* dout = (float*)d_out;                        // 2050 floats

  hipLaunchKernelGGL(k_hraw, dim3(2048), dim3(128), 0, stream, xfeat, W, bias, hraw, rowslot, norms);
  hipLaunchKernelGGL(k_bca, dim3(1563), dim3(256), 0, stream, items, ib, norms);
  hipLaunchKernelGGL(k_bnstats, dim3(128), dim3(256), 0, stream, hraw, meanv, rsv);
  hipLaunchKernelGGL(k_apply, dim3(1024), dim3(256), 0, stream, hraw, meanv, rsv, gamma, beta, hfin, hb, norms);
  hipLaunchKernelGGL(k_seed, dim3(512), dim3(256), 0, stream, hfin, items, V0);
  hipLaunchKernelGGL(k_screen, dim3(2048), dim3(256), 0, stream, hb, hfin, items, ib, V0, norms, rowslot);
  hipLaunchKernelGGL(k_final, dim3(2048), dim3(64), 0, stream, rowslot, uid, items, dout, simv);
  hipLaunchKernelGGL(k_reduce, dim3(1), dim3(256), 0, stream, simv, dout);
}

// Round 15
// 376.562 us; speedup vs baseline: 1.0952x; 1.0815x over previous
//
#include <hip/hip_runtime.h>
#include <math.h>

#define TINYF 1.17549435e-38f
#define GMAX 16.0f   // hard upper bound on gumbel (15.9424) + slack
#define NT16 3125    // 50000 / 16 exactly
#define SPT16 49     // tiles per span (64 spans x 49 >= 3125)

typedef __attribute__((ext_vector_type(8))) short bf16x8;
typedef __attribute__((ext_vector_type(4))) float f32x4;

// ---------------- threefry2x32, key = (0, 42) ----------------
__device__ __forceinline__ unsigned rotl32(unsigned x, int r) {
  return (x << r) | (x >> (32 - r));
}

__device__ __forceinline__ unsigned tf2x32_xor(unsigned x0, unsigned x1) {
  const unsigned k0 = 0u, k1 = 42u, k2 = 0x1BD11BF0u;  // 0x1BD11BDA ^ 0 ^ 42
  x0 += k0; x1 += k1;
#define TFR(r) { x0 += x1; x1 = rotl32(x1, r); x1 ^= x0; }
  TFR(13) TFR(15) TFR(26) TFR(6)
  x0 += k1; x1 += k2 + 1u;
  TFR(17) TFR(29) TFR(16) TFR(24)
  x0 += k2; x1 += k0 + 2u;
  TFR(13) TFR(15) TFR(26) TFR(6)
  x0 += k0; x1 += k1 + 3u;
  TFR(17) TFR(29) TFR(16) TFR(24)
  x0 += k1; x1 += k2 + 4u;
  TFR(13) TFR(15) TFR(26) TFR(6)
  x0 += k2; x1 += k0 + 5u;
#undef TFR
  return x0 ^ x1;
}

__device__ __forceinline__ float gumbel_from_bits(unsigned bits) {
  float f = __uint_as_float((bits >> 9) | 0x3f800000u) - 1.0f;
  float u = fmaxf(f, TINYF);
  return -logf(-logf(u));
}

// order-preserving float->uint (monotone)
__device__ __forceinline__ unsigned ordf(float v) {
  unsigned b = __float_as_uint(v);
  return (b & 0x80000000u) ? ~b : (b | 0x80000000u);
}
__device__ __forceinline__ float unordf(unsigned u) {
  unsigned b = (u & 0x80000000u) ? (u & 0x7FFFFFFFu) : ~u;
  return __uint_as_float(b);
}

// fp32 -> bf16 RNE (bit trick)
__device__ __forceinline__ unsigned short f2bf(float f) {
  unsigned u = __float_as_uint(f);
  unsigned r = u + 0x7FFFu + ((u >> 16) & 1u);
  return (unsigned short)(r >> 16);
}
__device__ __forceinline__ unsigned pk2(float a, float b) {
  return (unsigned)f2bf(a) | ((unsigned)f2bf(b) << 16);
}
// XOR swizzle within a 16-row x 256B tile (kills stride-256B bank conflicts)
__device__ __forceinline__ int bswz(int b) { return b ^ (((b >> 8) & 7) << 4); }

// ---- candidate resolution. Fresh tier-2 threshold from rowslot (tighter,
// still sound). Fast u-space pre-test with HW exp (no false reject, ~2e-5
// over-accept filtered by the exact path). ONE noinline copy, dense drains.
__device__ __attribute__((noinline)) void resolve_cand(
    int R, int J, float s, float ERRC,
    const float* __restrict__ hfin, const float* __restrict__ items,
    const float* __restrict__ V0,
    unsigned long long* __restrict__ rowslot, const volatile unsigned* hiw) {
  const unsigned hi0 = hiw[2 * R + 1];
  float tv = V0[R];
  if (hi0) tv = fmaxf(tv, unordf(hi0));
  const float thr2 = tv - ERRC;  // sound: s_fp32 + g <= s_bf16 + ERRC + g
  const float d = thr2 - s;
  const unsigned bits = tf2x32_xor(0u, (unsigned)R * 50000u + (unsigned)J);
  const float f = __uint_as_float((bits >> 9) | 0x3f800000u) - 1.0f;
  const float u = fmaxf(f, TINYF);
  const float thr_u = __expf(-__expf(-d)) * (1.0f - 2e-5f);
  if (u < thr_u) return;             // sound fast reject
  const float g = -logf(-logf(u));   // exact gumbel (rare path)
  if (s + g < thr2) return;          // exact tier-2
  const float4* hp = (const float4*)(hfin + (size_t)R * 128);
  const float4* ap = (const float4*)(items + (size_t)J * 128);
  float4 a4 = {0.f, 0.f, 0.f, 0.f};
#pragma unroll
  for (int k = 0; k < 32; ++k) {
    float4 h = hp[k];
    float4 b = ap[k];
    a4.x = fmaf(h.x, b.x, a4.x);
    a4.y = fmaf(h.y, b.y, a4.y);
    a4.z = fmaf(h.z, b.z, a4.z);
    a4.w = fmaf(h.w, b.w, a4.w);
  }
  const float v = ((a4.x + a4.y) + (a4.z + a4.w)) + g;
  const unsigned ov = ordf(v);
  if (ov >= hiw[2 * R + 1]) {  // '>=': let atomicMax resolve smaller-J ties
    const unsigned long long pk =
        ((unsigned long long)ov << 32) | (0xFFFFFFFFu - (unsigned)J);
    atomicMax(&rowslot[R], pk);
  }
}

// ---------------- h = x @ W + b (f64 accumulate) + workspace init ----------
__global__ void k_hraw(const float* __restrict__ x, const float* __restrict__ W,
                       const float* __restrict__ b, float* __restrict__ hraw,
                       unsigned long long* __restrict__ rowslot,
                       float* __restrict__ norms) {
  __shared__ float sx[256];
  const int i = blockIdx.x;
  const int d = threadIdx.x;  // 128 threads
  if (d == 0) {
    rowslot[i] = 0ull;
    if (i == 0) { norms[0] = 0.0f; norms[1] = 0.0f; }
  }
  sx[d] = x[i * 256 + d];
  sx[d + 128] = x[i * 256 + 128 + d];
  __syncthreads();
  double acc = 0.0;
  for (int k = 0; k < 256; ++k)
    acc = fma((double)sx[k], (double)W[k * 128 + d], acc);
  hraw[i * 128 + d] = (float)acc + b[d];
}

// ---- items fp32 -> bf16 (RNE, same bits) + max row-norm^2, one pass -------
// Launched AFTER k_hraw (stream order) so norms[1]=0 init precedes atomics.
__global__ void k_bca(const float* __restrict__ items,
                      unsigned short* __restrict__ ib,
                      float* __restrict__ norms) {
  __shared__ float red[4];
  const int t = threadIdx.x;
  const int row = blockIdx.x * 32 + (t >> 3);
  const int rc = row > 49999 ? 49999 : row;  // dup row: harmless for max
  const int c = (t & 7) * 16;
  const float4* p = (const float4*)(items + (size_t)rc * 128 + c);
  const float4 v0 = p[0], v1 = p[1], v2 = p[2], v3 = p[3];
  float ss = v0.x * v0.x + v0.y * v0.y + v0.z * v0.z + v0.w * v0.w +
             v1.x * v1.x + v1.y * v1.y + v1.z * v1.z + v1.w * v1.w +
             v2.x * v2.x + v2.y * v2.y + v2.z * v2.z + v2.w * v2.w +
             v3.x * v3.x + v3.y * v3.y + v3.z * v3.z + v3.w * v3.w;
  if (row <= 49999) {
    uint4 o0, o1;
    o0.x = pk2(v0.x, v0.y); o0.y = pk2(v0.z, v0.w);
    o0.z = pk2(v1.x, v1.y); o0.w = pk2(v1.z, v1.w);
    o1.x = pk2(v2.x, v2.y); o1.y = pk2(v2.z, v2.w);
    o1.z = pk2(v3.x, v3.y); o1.w = pk2(v3.z, v3.w);
    uint4* dst = (uint4*)(ib + (size_t)row * 128 + c);
    dst[0] = o0; dst[1] = o1;
  }
  ss += __shfl_xor(ss, 1);  // sum 8-lane row group
  ss += __shfl_xor(ss, 2);
  ss += __shfl_xor(ss, 4);
  ss = fmaxf(ss, __shfl_xor(ss, 8));   // max across rows in wave
  ss = fmaxf(ss, __shfl_xor(ss, 16));
  ss = fmaxf(ss, __shfl_xor(ss, 32));
  if ((t & 63) == 0) red[t >> 6] = ss;
  __syncthreads();
  if (t == 0) {
    float mx = fmaxf(fmaxf(red[0], red[1]), fmaxf(red[2], red[3]));
    atomicMax((unsigned*)&norms[1], __float_as_uint(mx));
  }
}

// ---------------- BN stats per column (f64) ----------------
__global__ void k_bnstats(const float* __restrict__ hraw,
                          float* __restrict__ meanv, float* __restrict__ rsv) {
  __shared__ double red[256];
  const int d = blockIdx.x;   // 128 blocks
  const int t = threadIdx.x;  // 256 threads
  double s = 0.0;
  for (int i = t; i < 2048; i += 256) s += (double)hraw[i * 128 + d];
  red[t] = s;
  __syncthreads();
  for (int off = 128; off > 0; off >>= 1) {
    if (t < off) red[t] += red[t + off];
    __syncthreads();
  }
  const float m = (float)(red[0] * (1.0 / 2048.0));
  __syncthreads();
  double v = 0.0;
  for (int i = t; i < 2048; i += 256) {
    float dd = __fsub_rn(hraw[i * 128 + d], m);
    v += (double)dd * (double)dd;
  }
  red[t] = v;
  __syncthreads();
  for (int off = 128; off > 0; off >>= 1) {
    if (t < off) red[t] += red[t + off];
    __syncthreads();
  }
  if (t == 0) {
    float var = (float)(red[0] * (1.0 / 2048.0));
    float vpe = __fadd_rn(var, 1e-5f);
    meanv[d] = m;
    rsv[d] = (float)(1.0 / sqrt((double)vpe));
  }
}

// ---------------- apply BN + leaky relu, emit bf16 copy + max row-norm ------
__global__ void k_apply(const float* __restrict__ hraw,
                        const float* __restrict__ meanv, const float* __restrict__ rsv,
                        const float* __restrict__ gamma, const float* __restrict__ beta,
                        float* __restrict__ hfin, unsigned short* __restrict__ hb,
                        float* __restrict__ norms) {
  __shared__ float red[256];
  const int t = threadIdx.x;
  const int idx = blockIdx.x * 256 + t;  // 2 rows per block
  const int d = idx & 127;
  float h = hraw[idx];
  float hn = __fadd_rn(__fmul_rn(__fmul_rn(__fsub_rn(h, meanv[d]), rsv[d]), gamma[d]), beta[d]);
  float o = (hn >= 0.0f) ? hn : __fmul_rn(0.01f, hn);
  hfin[idx] = o;
  hb[idx] = f2bf(o);
  red[t] = o * o;
  __syncthreads();
  for (int off = 64; off > 0; off >>= 1) {
    if ((t & 127) < off) red[t] += red[t + off];
    __syncthreads();
  }
  if ((t & 127) == 0) atomicMax((unsigned*)&norms[0], __float_as_uint(red[t]));
}

// ---------------- V0 seed: per-row achieved max over j in [0,1024) ----------
__global__ __launch_bounds__(256, 4) void k_seed(const float* __restrict__ hfin,
                                                 const float* __restrict__ items,
                                                 float* __restrict__ V0) {
  __shared__ float red[4][256];
  const int t = threadIdx.x;
  const int rbase = blockIdx.x * 4;
  float best[4] = {-INFINITY, -INFINITY, -INFINITY, -INFINITY};
  for (int q = 0; q < 4; ++q) {
    const int j = t + 256 * q;
    float acc[4] = {0.0f, 0.0f, 0.0f, 0.0f};
    const float* ap = items + (size_t)j * 128;
    for (int km = 0; km < 8; ++km) {
#pragma unroll
      for (int e = 0; e < 4; ++e) {
        float4 a4 = *(const float4*)(ap + km * 16 + 4 * e);
#pragma unroll
        for (int p = 0; p < 4; ++p) {
          const float* hp = hfin + (rbase + p) * 128 + km * 16 + 4 * e;
          float4 h4 = *(const float4*)hp;  // uniform -> s_load
          acc[p] = fmaf(h4.x, a4.x, acc[p]);
          acc[p] = fmaf(h4.y, a4.y, acc[p]);
          acc[p] = fmaf(h4.z, a4.z, acc[p]);
          acc[p] = fmaf(h4.w, a4.w, acc[p]);
        }
      }
    }
#pragma unroll
    for (int p = 0; p < 4; ++p) {
      unsigned l = (unsigned)(rbase + p) * 50000u + (unsigned)j;
      float g = gumbel_from_bits(tf2x32_xor(0u, l));
      best[p] = fmaxf(best[p], acc[p] + g);
    }
  }
#pragma unroll
  for (int p = 0; p < 4; ++p) red[p][t] = best[p];
  __syncthreads();
  for (int off = 128; off > 0; off >>= 1) {
    if (t < off) {
#pragma unroll
      for (int p = 0; p < 4; ++p) red[p][t] = fmaxf(red[p][t], red[p][t + off]);
    }
    __syncthreads();
  }
  if (t < 4) V0[rbase + t] = red[t][0];
}

// ---------------- bf16 MFMA screen: ZERO-barrier wave-private pipeline -----
// grid 2048 = rg*64 + span (rg 0..31, span 0..63; bid%8 = span%8 -> XCD-
// local j-window). 4 INDEPENDENT waves/block, NO __syncthreads anywhere.
// Each wave: 16 rows x 49 tiles of 16 j; PRIVATE 2 x 4KB LDS double-buffer;
// per-iter: issue 4 global_load_lds for tile t+1 -> s_waitcnt vmcnt(4)
// (counted -- old batch retires, new stays in flight; asm + memory clobber +
// sched_barrier per guide rule 18) -> 4 ds_read_b128 + 4 chained MFMA ->
// ballot-push -> per-wave drain at >=64. The rounds-9..14 plateau at ~230us
// tracked the per-iter block barrier (4-wave convoy + full vmcnt0 drain);
// this removes it entirely. LDS 36KB/block -> 4 blocks/CU = 50% occ cap.
__global__ __launch_bounds__(256, 2) void k_screen(
    const unsigned short* __restrict__ hb, const float* __restrict__ hfin,
    const float* __restrict__ items, const unsigned short* __restrict__ ib,
    const float* __restrict__ V0,
    const float* __restrict__ norms, unsigned long long* __restrict__ rowslot) {
  __shared__ __align__(16) unsigned short Bs[4][2][16 * 128];  // 32KB: [wave][dbuf][4KB]
  __shared__ unsigned qk[4][128];  // per-wave candidate queues
  __shared__ float qsh[4][128];

  const int t = threadIdx.x;
  const int w = t >> 6, l = t & 63;
  const int lg = l >> 4, lr = l & 15;
  const int rg = blockIdx.x >> 6;       // 0..31
  const int span = blockIdx.x & 63;
  const int r0w = rg * 64 + w * 16;     // this wave's 16 rows
  const int tile0 = span * SPT16;
  int nt = NT16 - tile0;
  nt = nt < 0 ? 0 : (nt > SPT16 ? SPT16 : nt);
  if (nt == 0) return;  // block-uniform (span 63 has 38)

  const float ERRC = 0.004f * sqrtf(norms[0] * norms[1]) + 0.01f;
  const volatile unsigned* hiw = (const volatile unsigned*)rowslot;  // hi @ 2R+1

  // resident A fragments: lane holds row (r0w + lr), 8 k each
  const unsigned short* aB0 = hb + (size_t)(r0w + lr) * 128 + lg * 8;
  bf16x8 Afrag[4];
#pragma unroll
  for (int kb = 0; kb < 4; ++kb) Afrag[kb] = *(const bf16x8*)(aB0 + kb * 32);

  // wave-private staging: chunk c covers LDS bytes [c*1024, +1024);
  // lane l -> LDS off c*1024 + l*16; tile-local row = c*4 + (l>>4),
  // col = (l&15)*16; swizzled global col = col ^ ((row&7)<<4).
  char* wlds = (char*)Bs + w * 8192;
  const char* ibc = (const char*)ib;
  int so[4];
#pragma unroll
  for (int c = 0; c < 4; ++c) {
    const int row = c * 4 + (l >> 4);
    const int col = (l & 15) * 16;
    so[c] = row * 256 + (col ^ ((row & 7) << 4));
  }

#define ISSUE(tl, pbuf)                                                        \
  {                                                                            \
    const char* gs = ibc + (size_t)(tl) * 4096;                                \
    char* ld = wlds + (pbuf) * 4096;                                           \
    __builtin_amdgcn_global_load_lds((const unsigned*)(gs + so[0]),            \
                                     (unsigned*)(ld), 16, 0, 0);               \
    __builtin_amdgcn_global_load_lds((const unsigned*)(gs + so[1]),            \
                                     (unsigned*)(ld + 1024), 16, 0, 0);        \
    __builtin_amdgcn_global_load_lds((const unsigned*)(gs + so[2]),            \
                                     (unsigned*)(ld + 2048), 16, 0, 0);        \
    __builtin_amdgcn_global_load_lds((const unsigned*)(gs + so[3]),            \
                                     (unsigned*)(ld + 3072), 16, 0, 0);        \
  }
#define WAITVM4() { asm volatile("s_waitcnt vmcnt(4)" ::: "memory"); \
                    __builtin_amdgcn_sched_barrier(0); }
#define WAITVM0() { asm volatile("s_waitcnt vmcnt(0)" ::: "memory"); \
                    __builtin_amdgcn_sched_barrier(0); }

  // prologue: stage tile0 -> buf 0
  ISSUE(tile0, 0)

  const unsigned long long lml = (1ull << l) - 1ull;  // lanes below me
  unsigned qn = 0;     // wave-uniform queue count (SGPR)
  float th1[4];        // tier-1 thresholds (registers)

  int pb = 0;
  for (int it = 0; it < nt; ++it) {
    const int j0 = (tile0 + it) * 16;

    // ---- issue next tile; counted wait retires ONLY the current tile ----
    if (it + 1 < nt) {
      ISSUE(tile0 + it + 1, pb ^ 1)
      WAITVM4()
    } else {
      WAITVM0()
    }

    // ---- refresh tier-1 thresholds every 8 tiles (stale-low is safe) ----
    if ((it & 7) == 0) {
      float tvl = 0.0f;
      if (l < 16) {
        const int R = r0w + l;
        const unsigned hi = hiw[2 * R + 1];
        tvl = V0[R];
        if (hi) tvl = fmaxf(tvl, unordf(hi));
      }
#pragma unroll
      for (int q = 0; q < 4; ++q)
        th1[q] = __shfl(tvl, lg * 4 + q) - GMAX - ERRC;
    }

    // ---- 4 ds_read + 4 chained MFMA from buf pb ----
    f32x4 acc = (f32x4){0.f, 0.f, 0.f, 0.f};
    const char* tb = wlds + pb * 4096;
#pragma unroll
    for (int kb = 0; kb < 4; ++kb) {
      bf16x8 bfrag = *(const bf16x8*)(tb + bswz(lr * 256 + kb * 64 + lg * 16));
      acc = __builtin_amdgcn_mfma_f32_16x16x32_bf16(Afrag[kb], bfrag, acc, 0, 0, 0);
    }

    // ---- tier-1 push via ballot compaction; per-wave drain at >=64 ----
    // C/D layout: col = lane&15 (lr) -> J = j0+lr; row = (lane>>4)*4 + q.
#pragma unroll
    for (int q = 0; q < 4; ++q) {
      const float s = acc[q];
      const int J = j0 + lr;
      const bool c = (s >= th1[q]);
      const unsigned long long m = __ballot(c);
      if (m) {
        if (c) {
          const unsigned idx = qn + (unsigned)__popcll(m & lml);
          qk[w][idx] = ((unsigned)(lg * 4 + q) << 16) | (unsigned)J;
          qsh[w][idx] = s;
        }
        qn += (unsigned)__popcll(m);
        if (qn >= 64) {  // drain fully (qn <= 127 -> fits cap 128)
          for (unsigned i = (unsigned)l; i < qn; i += 64) {
            const unsigned key = qk[w][i];
            resolve_cand(r0w + (int)(key >> 16), (int)(key & 0xFFFFu),
                         qsh[w][i], ERRC, hfin, items, V0, rowslot, hiw);
          }
          qn = 0;
        }
      }
    }

    pb ^= 1;
  }

  // ---- final drain ----
  for (unsigned i = (unsigned)l; i < qn; i += 64) {
    const unsigned key = qk[w][i];
    resolve_cand(r0w + (int)(key >> 16), (int)(key & 0xFFFFu),
                 qsh[w][i], ERRC, hfin, items, V0, rowslot, hiw);
  }
#undef ISSUE
#undef WAITVM4
#undef WAITVM0
}

// ---------------- final: read row winner + cosine sim (one wave/row) -------
__global__ void k_final(const unsigned long long* __restrict__ rowslot,
                        const int* __restrict__ uid, const float* __restrict__ items,
                        float* __restrict__ dout, float* __restrict__ simv) {
  const int r = blockIdx.x;
  const int lane = threadIdx.x;  // 64
  const unsigned long long pk = rowslot[r];  // nonzero: winner always pushed
  const int bi = (int)(0xFFFFFFFFu - (unsigned)pk);
  if (lane == 0) dout[r] = (float)bi;

  const int orig = uid[r * 2 + 1];
  float o1 = items[(size_t)orig * 128 + lane];
  float o2 = items[(size_t)orig * 128 + 64 + lane];
  float p1 = items[(size_t)bi * 128 + lane];
  float p2 = items[(size_t)bi * 128 + 64 + lane];
  float d = o1 * p1 + o2 * p2;
  float s1 = o1 * o1 + o2 * o2;
  float s2 = p1 * p1 + p2 * p2;
  for (int off = 32; off > 0; off >>= 1) {
    d += __shfl_down(d, off);
    s1 += __shfl_down(s1, off);
    s2 += __shfl_down(s2, off);
  }
  if (lane == 0) {
    float n1 = fmaxf(sqrtf(s1), 1e-6f);
    float n2 = fmaxf(sqrtf(s2), 1e-6f);
    float sim = d / (n1 * n2);
    simv[r] = (sim + 1.0f) * 0.5f;
  }
}

// ---------------- final scalar reductions ----------------
__global__ void k_reduce(const float* __restrict__ simv, float* __restrict__ dout) {
  __shared__ double rl[256];
  __shared__ double rs[256];
  const int t = threadIdx.x;
  double L = 0.0, S = 0.0;
  for (int i = t; i < 2048; i += 256) {
    double s = (double)simv[i];
    double dd = s - 0.5;
    L += dd * dd;
    S += s;
  }
  rl[t] = L; rs[t] = S;
  __syncthreads();
  for (int off = 128; off > 0; off >>= 1) {
    if (t < off) { rl[t] += rl[t + off]; rs[t] += rs[t + off]; }
    __syncthreads();
  }
  if (t == 0) {
    dout[2048] = (float)(rl[0] * (1.0 / 2048.0));
    dout[2049] = (float)(rs[0] * (1.0 / 2048.0));
  }
}

extern "C" void kernel_launch(void* const* d_in, const int* in_sizes, int n_in,
                              void* d_out, int out_size, void* d_ws, size_t ws_size,
                              hipStream_t stream) {
  const int* uid = (const int*)d_in[0];       // (2048,2) int32
  const float* xfeat = (const float*)d_in[1]; // (2048,256)
  const float* items = (const float*)d_in[2]; // (50000,128)
  const float* W = (const float*)d_in[3];     // (256,128)
  const float* bias = (const float*)d_in[4];  // (128,)
  const float* gamma = (const float*)d_in[5]; // (128,)
  const float* beta = (const float*)d_in[6];  // (128,)

  float* ws = (float*)d_ws;
  float* hraw = ws;                                   // 262144 f
  float* hfin = ws + 262144;                          // 262144 f
  float* meanv = ws + 524288;                         // 128 f
  float* rsv = ws + 524416;                           // 128 f
  float* V0 = ws + 524544;                            // 2048 f
  float* simv = ws + 526592;                          // 2048 f
  float* norms = ws + 528640;                         // 2 f (Hmax^2, Amax^2)
  unsigned long long* rowslot =
      (unsigned long long*)(ws + 528642);             // 2048 u64 (8B aligned)
  unsigned short* hb = (unsigned short*)(ws + 532740); // 262144 bf16
  unsigned short* ib = (unsigned short*)(ws + 663812); // 12.8MB bf16 (16B aligned)
  float* dout = (float*)d_out;                        // 2050 floats

  hipLaunchKernelGGL(k_hraw, dim3(2048), dim3(128), 0, stream, xfeat, W, bias, hraw, rowslot, norms);
  hipLaunchKernelGGL(k_bca, dim3(1563), dim3(256), 0, stream, items, ib, norms);
  hipLaunchKernelGGL(k_bnstats, dim3(128), dim3(256), 0, stream, hraw, meanv, rsv);
  hipLaunchKernelGGL(k_apply, dim3(1024), dim3(256), 0, stream, hraw, meanv, rsv, gamma, beta, hfin, hb, norms);
  hipLaunchKernelGGL(k_seed, dim3(512), dim3(256), 0, stream, hfin, items, V0);
  hipLaunchKernelGGL(k_screen, dim3(2048), dim3(256), 0, stream, hb, hfin, items, ib, V0, norms, rowslot);
  hipLaunchKernelGGL(k_final, dim3(2048), dim3(64), 0, stream, rowslot, uid, items, dout, simv);
  hipLaunchKernelGGL(k_reduce, dim3(1), dim3(256), 0, stream, simv, dout);
}